// Round 2
// baseline (182.118 us; speedup 1.0000x reference)
//
#include <hip/hip_runtime.h>

// ROI Align on MI355X.
// input: (N=8, C=256, H=100, W=100) fp32 NCHW; rois (K,5); out (K,256,7,7) fp32.
//
// Round 12 (= round 11 + compile fix): gather inner loop rebuilt around a
// per-block descriptor table. All 784 (bin,sample,corner) -> {byte_off,
// weight} tuples precomputed into LDS (6.3 KB); inner loop = broadcast
// ds_read_b64 + uint4 corner load + 8 fma. Lanes remapped c*4+q so corner
// reduce is quad-local shfl_xor(1/2). 2-bin software pipeline (static A/B
// regs) hides L2 latency. Waves own contiguous bin ranges for L1 corner
// reuse. Transpose input loads nontemporal (via ext_vector float4 — the
// HIP_vector_type float4 is rejected by __builtin_nontemporal_load).

typedef float nfloat4 __attribute__((ext_vector_type(4)));

constexpr int   OUT_H = 7;
constexpr int   OUT_W = 7;
constexpr int   NBINS = OUT_H * OUT_W;          // 49
constexpr float SPATIAL_SCALE = 0.25f;
constexpr int   SR = 2;
constexpr int   N_DIM = 8;
constexpr int   C_DIM = 256;
constexpr int   H_DIM = 100;
constexpr int   W_DIM = 100;
constexpr int   HW    = H_DIM * W_DIM;          // 10000
constexpr size_t NHWC_BF16_BYTES = (size_t)N_DIM * HW * C_DIM * 2; // 40,960,000
constexpr int   MAX_BUCKET_K = 2048;

__device__ inline unsigned short f2bf_rne(float f) {
    unsigned u = __float_as_uint(f);
    u += 0x7fffu + ((u >> 16) & 1u);    // round-to-nearest-even
    return (unsigned short)(u >> 16);
}

// ---------------- transpose+cast + bucket (fused) ---------------------------
// blocks x<157: NCHW fp32 -> NHWC bf16, 64ch x 64sp tile, LDS stride 65.
// block (157,0,0): bucket -> map[k] = ROI index with batch ~= k%8.
constexpr int TP = 65;

union TransposeSh {
    float tile[64 * TP];                                   // 16640 B
    struct {
        int cnt[8]; int ovfCnt; int holeCnt;
        int ovf[MAX_BUCKET_K]; int holes[MAX_BUCKET_K];    // 16424 B
    } bk;
};

__global__ __launch_bounds__(256) void nchw_to_nhwc_bf16(
    const float* __restrict__ in, unsigned short* __restrict__ out,
    const float* __restrict__ rois, int K, int* __restrict__ map)
{
    __shared__ TransposeSh sh;
    int bx = blockIdx.x;
    int t  = threadIdx.x;

    if (bx == (HW + 63) / 64) {
        // ---- bucket branch: one block does the batch->position map ----
        if (blockIdx.y != 0 || blockIdx.z != 0 || map == nullptr) return;
        if (t < 8) sh.bk.cnt[t] = 0;
        if (t == 0) { sh.bk.ovfCnt = 0; sh.bk.holeCnt = 0; }
        for (int i = t; i < K; i += 256) map[i] = -1;
        __syncthreads();
        int per = K / 8;
        for (int i = t; i < K; i += 256) {
            int b = ((int)rois[(size_t)i * 5]) & 7;
            int r = atomicAdd(&sh.bk.cnt[b], 1);
            if (r < per) map[b + 8 * r] = i;
            else sh.bk.ovf[atomicAdd(&sh.bk.ovfCnt, 1)] = i;
        }
        __syncthreads();
        for (int i = t; i < K; i += 256)
            if (map[i] == -1) sh.bk.holes[atomicAdd(&sh.bk.holeCnt, 1)] = i;
        __syncthreads();
        for (int i = t; i < sh.bk.ovfCnt; i += 256)
            map[sh.bk.holes[i]] = sh.bk.ovf[i];
        return;
    }

    // ---- transpose branch ----
    int s0 = bx * 64;
    int c0 = blockIdx.y * 64;
    int n  = blockIdx.z;

    int sl4 = (t & 15) * 4;
    int cq  = t >> 4;                  // 0..15

    #pragma unroll
    for (int r = 0; r < 4; ++r) {
        int cl = r * 16 + cq;
        int s  = s0 + sl4;
        const float* src = in + ((size_t)(n * C_DIM + c0 + cl) * HW + s);
        if (s + 3 < HW) {
            nfloat4 v = __builtin_nontemporal_load((const nfloat4*)src);
            sh.tile[cl * TP + sl4 + 0] = v.x;
            sh.tile[cl * TP + sl4 + 1] = v.y;
            sh.tile[cl * TP + sl4 + 2] = v.z;
            sh.tile[cl * TP + sl4 + 3] = v.w;
        } else {
            #pragma unroll
            for (int i = 0; i < 4; ++i)
                sh.tile[cl * TP + sl4 + i] = (s + i < HW) ? src[i] : 0.0f;
        }
    }
    __syncthreads();

    int cl4 = (t & 15) * 4;
    #pragma unroll
    for (int r = 0; r < 4; ++r) {
        int sl = r * 16 + cq;
        int s  = s0 + sl;
        if (s < HW) {
            ushort4 h;
            h.x = f2bf_rne(sh.tile[(cl4 + 0) * TP + sl]);
            h.y = f2bf_rne(sh.tile[(cl4 + 1) * TP + sl]);
            h.z = f2bf_rne(sh.tile[(cl4 + 2) * TP + sl]);
            h.w = f2bf_rne(sh.tile[(cl4 + 3) * TP + sl]);
            *(ushort4*)(out + ((size_t)n * HW + s) * C_DIM + c0 + cl4) = h;
        }
    }
}

// ---------------- gather: descriptor table + pipelined corner loads ---------
// block = (ROI via map, 128-ch half); wave = contiguous bin range;
// lane = c*4+q (c = 8-ch group, q = corner). Descriptor table in LDS holds
// {byte_off, weight} for all 49*4*4 (bin,sample,corner) tuples; weight has
// validity premultiplied. Inner loop: ds_read_b64 + uint4 load + 8 fma;
// 2-bin software pipeline with statically-named A/B register buffers.
struct alignas(16) Geom { int lo; int hi; float wv; float mwv; };
struct alignas(8)  Desc { int off; float w; };

__global__ __launch_bounds__(256) void roi_gather_q(
    const unsigned short* __restrict__ nhwc,
    const float* __restrict__ rois,
    const int* __restrict__ map,
    float* __restrict__ out, int K)
{
    __shared__ float s_out[128 * NBINS];   // 25088 B
    __shared__ Geom xg[OUT_W * SR];        // 14
    __shared__ Geom yg[OUT_H * SR];        // 14
    __shared__ Desc desc[NBINS * SR * SR * 4];  // 784 * 8 B = 6272 B

    int k = map ? map[blockIdx.x] : (int)blockIdx.x;
    int h = blockIdx.y;                    // channel half
    const float* r = rois + (size_t)k * 5;
    int   b  = (int)r[0];
    float x1 = r[1] * SPATIAL_SCALE;
    float y1 = r[2] * SPATIAL_SCALE;
    float x2 = r[3] * SPATIAL_SCALE;
    float y2 = r[4] * SPATIAL_SCALE;
    float roi_w = fmaxf(x2 - x1, 1.0f);
    float roi_h = fmaxf(y2 - y1, 1.0f);
    float bin_h = roi_h / (float)OUT_H;
    float bin_w = roi_w / (float)OUT_W;

    int t = threadIdx.x;
    // fill geometry: threads 0..13 -> x, 64..77 -> y (separate waves)
    if (t < OUT_W * SR) {
        float g = x1 + bin_w * (((float)t + 0.5f) * 0.5f);
        float v = (g >= -1.0f && g <= (float)W_DIM) ? 1.0f : 0.0f;
        float x = fminf(fmaxf(g, 0.0f), (float)(W_DIM - 1));
        int   lo = (int)floorf(x);
        float l  = x - (float)lo;
        xg[t].lo = lo; xg[t].hi = min(lo + 1, W_DIM - 1);
        xg[t].wv = l * v; xg[t].mwv = (1.0f - l) * v;
    } else if (t >= 64 && t < 64 + OUT_H * SR) {
        int i = t - 64;
        float g = y1 + bin_h * (((float)i + 0.5f) * 0.5f);
        float v = (g >= -1.0f && g <= (float)H_DIM) ? 1.0f : 0.0f;
        float y = fminf(fmaxf(g, 0.0f), (float)(H_DIM - 1));
        int   lo = (int)floorf(y);
        float l  = y - (float)lo;
        yg[i].lo = lo; yg[i].hi = min(lo + 1, H_DIM - 1);
        yg[i].wv = l * v; yg[i].mwv = (1.0f - l) * v;
    }
    __syncthreads();

    // fill descriptor table: e = bin*16 + (sy*2+sx)*4 + q
    for (int e = t; e < NBINS * 16; e += 256) {
        int bin = e >> 4;
        int s   = (e >> 2) & 3;
        int q   = e & 3;
        int oh  = bin / OUT_W;
        int ow  = bin - oh * OUT_W;
        Geom gy = yg[oh * SR + (s >> 1)];
        Geom gx = xg[ow * SR + (s & 1)];
        int   yy = (q & 2) ? gy.hi : gy.lo;
        float wy = (q & 2) ? gy.wv : gy.mwv;
        int   xx = (q & 1) ? gx.hi : gx.lo;
        float wx = (q & 1) ? gx.wv : gx.mwv;
        desc[e].off = (yy * W_DIM + xx) * (C_DIM * 2);   // byte offset in image
        desc[e].w   = wy * wx;
    }
    __syncthreads();

    int wave = t >> 6;
    int lane = t & 63;
    int q    = lane & 3;                   // corner: 0=ll 1=lh 2=hl 3=hh
    int c    = lane >> 2;                  // 8-channel group within half

    const char* img = (const char*)(nhwc + (size_t)b * HW * C_DIM + h * 128 + c * 8);

    // contiguous bin range per wave: 12/12/12/13
    int bin  = (wave * NBINS) >> 2;
    int bend = ((wave + 1) * NBINS) >> 2;

    float wA[4], wB[4];
    uint4 vA[4], vB[4];

    auto fetch = [&](int bb, float* w, uint4* v) {
        #pragma unroll
        for (int s = 0; s < 4; ++s) {
            Desc d = desc[bb * 16 + s * 4 + q];
            w[s] = d.w;
            v[s] = *(const uint4*)(img + d.off);
        }
    };
    auto process = [&](int bb, const float* w, const uint4* v) {
        float acc[8] = {0.f, 0.f, 0.f, 0.f, 0.f, 0.f, 0.f, 0.f};
        #pragma unroll
        for (int s = 0; s < 4; ++s) {
            float ww = w[s];
            #define ACCP(j, u) { \
                acc[2*(j)+0] = fmaf(ww, __uint_as_float((u) << 16),          acc[2*(j)+0]); \
                acc[2*(j)+1] = fmaf(ww, __uint_as_float((u) & 0xffff0000u),  acc[2*(j)+1]); }
            ACCP(0, v[s].x) ACCP(1, v[s].y) ACCP(2, v[s].z) ACCP(3, v[s].w)
            #undef ACCP
        }
        // reduce the 4 corners: quad-local (lanes 4c..4c+3 hold partials)
        #pragma unroll
        for (int j = 0; j < 8; ++j) {
            acc[j] += __shfl_xor(acc[j], 1);
            acc[j] += __shfl_xor(acc[j], 2);
        }
        if (q == 0) {
            #pragma unroll
            for (int j = 0; j < 8; ++j)
                s_out[(c * 8 + j) * NBINS + bb] = acc[j] * 0.25f;
        }
    };

    // 2-bin software pipeline with static A/B buffers
    fetch(bin, wA, vA);
    while (true) {
        int nxt = bin + 1;
        if (nxt < bend) fetch(nxt, wB, vB);
        process(bin, wA, vA);
        if (nxt >= bend) break;
        bin = nxt + 1;
        if (bin < bend) fetch(bin, wA, vA);
        process(nxt, wB, vB);
        if (bin >= bend) break;
    }
    __syncthreads();

    // coalesced nontemporal copy-out: 6272 floats = 1568 float4, contiguous
    nfloat4* o4 = (nfloat4*)(out + (size_t)k * (C_DIM * NBINS) + (size_t)h * 128 * NBINS);
    const nfloat4* s4 = (const nfloat4*)s_out;
    for (int i = t; i < (128 * NBINS) / 4; i += 256)
        __builtin_nontemporal_store(s4[i], o4 + i);
}

// ---------------- fallback (round-0 baseline) if ws too small ---------------
__global__ __launch_bounds__(256) void roi_align_naive(
    const float* __restrict__ input, const float* __restrict__ rois,
    float* __restrict__ out, int K)
{
    int idx = blockIdx.x * blockDim.x + threadIdx.x;
    int total = K * C_DIM * OUT_H * OUT_W;
    if (idx >= total) return;
    int ow = idx % OUT_W;
    int oh = (idx / OUT_W) % OUT_H;
    int c  = (idx / (OUT_W * OUT_H)) % C_DIM;
    int k  = idx / (OUT_W * OUT_H * C_DIM);
    const float* r = rois + (size_t)k * 5;
    int   b  = (int)r[0];
    float x1 = r[1] * SPATIAL_SCALE, y1 = r[2] * SPATIAL_SCALE;
    float x2 = r[3] * SPATIAL_SCALE, y2 = r[4] * SPATIAL_SCALE;
    float roi_w = fmaxf(x2 - x1, 1.0f), roi_h = fmaxf(y2 - y1, 1.0f);
    float bin_h = roi_h / OUT_H, bin_w = roi_w / OUT_W;
    const float* inp = input + ((size_t)b * C_DIM + c) * HW;
    float acc = 0.0f;
    #pragma unroll
    for (int sy = 0; sy < SR; ++sy) {
        float gy = y1 + bin_h * (((float)(oh * SR + sy) + 0.5f) / SR);
        bool vy = (gy >= -1.0f) && (gy <= (float)H_DIM);
        float y = fminf(fmaxf(gy, 0.0f), (float)(H_DIM - 1));
        int yl = (int)floorf(y); float ly = y - yl; int yh = min(yl + 1, H_DIM - 1);
        #pragma unroll
        for (int sx = 0; sx < SR; ++sx) {
            float gx = x1 + bin_w * (((float)(ow * SR + sx) + 0.5f) / SR);
            bool vx = (gx >= -1.0f) && (gx <= (float)W_DIM);
            float x = fminf(fmaxf(gx, 0.0f), (float)(W_DIM - 1));
            int xl = (int)floorf(x); float lx = x - xl; int xh = min(xl + 1, W_DIM - 1);
            float v = (1.0f - ly) * ((1.0f - lx) * inp[yl * W_DIM + xl] + lx * inp[yl * W_DIM + xh])
                    + ly * ((1.0f - lx) * inp[yh * W_DIM + xl] + lx * inp[yh * W_DIM + xh]);
            if (vy && vx) acc += v;
        }
    }
    out[idx] = acc * 0.25f;
}

extern "C" void kernel_launch(void* const* d_in, const int* in_sizes, int n_in,
                              void* d_out, int out_size, void* d_ws, size_t ws_size,
                              hipStream_t stream) {
    const float* input = (const float*)d_in[0];
    const float* rois  = (const float*)d_in[1];
    float* out = (float*)d_out;
    int K = in_sizes[1] / 5;
    int ntiles = (HW + 63) / 64;    // 157

    if (ws_size >= NHWC_BF16_BYTES + (size_t)K * sizeof(int) && K <= MAX_BUCKET_K) {
        unsigned short* nhwc = (unsigned short*)d_ws;
        int* map = (int*)((char*)d_ws + NHWC_BF16_BYTES);
        dim3 tgrid(ntiles + 1, C_DIM / 64, N_DIM);   // 158 x 4 x 8 (+1 = bucket block)
        nchw_to_nhwc_bf16<<<tgrid, 256, 0, stream>>>(input, nhwc, rois, K, map);
        dim3 ggrid(K, 2);
        roi_gather_q<<<ggrid, 256, 0, stream>>>(nhwc, rois, map, out, K);
    } else if (ws_size >= NHWC_BF16_BYTES) {
        unsigned short* nhwc = (unsigned short*)d_ws;
        dim3 tgrid(ntiles, C_DIM / 64, N_DIM);
        nchw_to_nhwc_bf16<<<tgrid, 256, 0, stream>>>(input, nhwc, rois, K, nullptr);
        dim3 ggrid(K, 2);
        roi_gather_q<<<ggrid, 256, 0, stream>>>(nhwc, rois, nullptr, out, K);
    } else {
        int total = K * C_DIM * OUT_H * OUT_W;
        roi_align_naive<<<(total + 255) / 256, 256, 0, stream>>>(input, rois, out, K);
    }
}

// Round 3
// 164.679 us; speedup vs baseline: 1.1059x; 1.1059x over previous
//
#include <hip/hip_runtime.h>

// ROI Align on MI355X.
// input: (N=8, C=256, H=100, W=100) fp32 NCHW; rois (K,5); out (K,256,7,7) fp32.
//
// Round 13: revert gather to the round-10 structure (lane = q*16+c, strided
// bins, Geom-in-LDS, register-computed addresses, 25.5 KB LDS -> 6 blocks/CU)
// after round-12's descriptor table regressed (ds_read chained in front of
// every global load + occupancy 6->4 blocks/CU; 57.9us latency-bound, all
// pipes <40%). Keep ONE round-12 idea: 2-bin software pipeline with static
// A/B register buffers, fed from register-computed offsets so next bin's 4
// uint4 corner loads issue before current bin's FMA/reduce/store.

typedef float nfloat4 __attribute__((ext_vector_type(4)));

constexpr int   OUT_H = 7;
constexpr int   OUT_W = 7;
constexpr int   NBINS = OUT_H * OUT_W;          // 49
constexpr float SPATIAL_SCALE = 0.25f;
constexpr int   SR = 2;
constexpr int   N_DIM = 8;
constexpr int   C_DIM = 256;
constexpr int   H_DIM = 100;
constexpr int   W_DIM = 100;
constexpr int   HW    = H_DIM * W_DIM;          // 10000
constexpr size_t NHWC_BF16_BYTES = (size_t)N_DIM * HW * C_DIM * 2; // 40,960,000
constexpr int   MAX_BUCKET_K = 2048;

__device__ inline unsigned short f2bf_rne(float f) {
    unsigned u = __float_as_uint(f);
    u += 0x7fffu + ((u >> 16) & 1u);    // round-to-nearest-even
    return (unsigned short)(u >> 16);
}

// ---------------- transpose+cast + bucket (fused) ---------------------------
// blocks x<157: NCHW fp32 -> NHWC bf16, 64ch x 64sp tile, LDS stride 65.
// block (157,0,0): bucket -> map[k] = ROI index with batch ~= k%8.
constexpr int TP = 65;

union TransposeSh {
    float tile[64 * TP];                                   // 16640 B
    struct {
        int cnt[8]; int ovfCnt; int holeCnt;
        int ovf[MAX_BUCKET_K]; int holes[MAX_BUCKET_K];    // 16424 B
    } bk;
};

__global__ __launch_bounds__(256) void nchw_to_nhwc_bf16(
    const float* __restrict__ in, unsigned short* __restrict__ out,
    const float* __restrict__ rois, int K, int* __restrict__ map)
{
    __shared__ TransposeSh sh;
    int bx = blockIdx.x;
    int t  = threadIdx.x;

    if (bx == (HW + 63) / 64) {
        // ---- bucket branch: one block does the batch->position map ----
        if (blockIdx.y != 0 || blockIdx.z != 0 || map == nullptr) return;
        if (t < 8) sh.bk.cnt[t] = 0;
        if (t == 0) { sh.bk.ovfCnt = 0; sh.bk.holeCnt = 0; }
        for (int i = t; i < K; i += 256) map[i] = -1;
        __syncthreads();
        int per = K / 8;
        for (int i = t; i < K; i += 256) {
            int b = ((int)rois[(size_t)i * 5]) & 7;
            int r = atomicAdd(&sh.bk.cnt[b], 1);
            if (r < per) map[b + 8 * r] = i;
            else sh.bk.ovf[atomicAdd(&sh.bk.ovfCnt, 1)] = i;
        }
        __syncthreads();
        for (int i = t; i < K; i += 256)
            if (map[i] == -1) sh.bk.holes[atomicAdd(&sh.bk.holeCnt, 1)] = i;
        __syncthreads();
        for (int i = t; i < sh.bk.ovfCnt; i += 256)
            map[sh.bk.holes[i]] = sh.bk.ovf[i];
        return;
    }

    // ---- transpose branch ----
    int s0 = bx * 64;
    int c0 = blockIdx.y * 64;
    int n  = blockIdx.z;

    int sl4 = (t & 15) * 4;
    int cq  = t >> 4;                  // 0..15

    #pragma unroll
    for (int r = 0; r < 4; ++r) {
        int cl = r * 16 + cq;
        int s  = s0 + sl4;
        const float* src = in + ((size_t)(n * C_DIM + c0 + cl) * HW + s);
        if (s + 3 < HW) {
            nfloat4 v = __builtin_nontemporal_load((const nfloat4*)src);
            sh.tile[cl * TP + sl4 + 0] = v.x;
            sh.tile[cl * TP + sl4 + 1] = v.y;
            sh.tile[cl * TP + sl4 + 2] = v.z;
            sh.tile[cl * TP + sl4 + 3] = v.w;
        } else {
            #pragma unroll
            for (int i = 0; i < 4; ++i)
                sh.tile[cl * TP + sl4 + i] = (s + i < HW) ? src[i] : 0.0f;
        }
    }
    __syncthreads();

    int cl4 = (t & 15) * 4;
    #pragma unroll
    for (int r = 0; r < 4; ++r) {
        int sl = r * 16 + cq;
        int s  = s0 + sl;
        if (s < HW) {
            ushort4 h;
            h.x = f2bf_rne(sh.tile[(cl4 + 0) * TP + sl]);
            h.y = f2bf_rne(sh.tile[(cl4 + 1) * TP + sl]);
            h.z = f2bf_rne(sh.tile[(cl4 + 2) * TP + sl]);
            h.w = f2bf_rne(sh.tile[(cl4 + 3) * TP + sl]);
            *(ushort4*)(out + ((size_t)n * HW + s) * C_DIM + c0 + cl4) = h;
        }
    }
}

// ---------------- gather: corner-quadrant + LDS geometry + 2-bin pipe -------
// block = (ROI via map, 128-ch half); wave = strided bins; lane = q*16+c.
// Geometry {lo, hi, l*v, (1-l)*v} for 14 x / 14 y sample positions computed
// once per block; per bin: 4 broadcast ds_read_b128 Geom + selects give the
// 4 corner byte offsets in REGISTERS; next bin's 4 uint4 loads are issued
// before the current bin's FMA/reduce/store (static A/B buffers).
struct alignas(16) Geom { int lo; int hi; float wv; float mwv; };

__global__ __launch_bounds__(256) void roi_gather_q(
    const unsigned short* __restrict__ nhwc,
    const float* __restrict__ rois,
    const int* __restrict__ map,
    float* __restrict__ out, int K)
{
    __shared__ float s_out[128 * NBINS];   // 25088 B
    __shared__ Geom xg[OUT_W * SR];        // 14
    __shared__ Geom yg[OUT_H * SR];        // 14

    int k = map ? map[blockIdx.x] : (int)blockIdx.x;
    int h = blockIdx.y;                    // channel half
    const float* r = rois + (size_t)k * 5;
    int   b  = (int)r[0];
    float x1 = r[1] * SPATIAL_SCALE;
    float y1 = r[2] * SPATIAL_SCALE;
    float x2 = r[3] * SPATIAL_SCALE;
    float y2 = r[4] * SPATIAL_SCALE;
    float roi_w = fmaxf(x2 - x1, 1.0f);
    float roi_h = fmaxf(y2 - y1, 1.0f);
    float bin_h = roi_h / (float)OUT_H;
    float bin_w = roi_w / (float)OUT_W;

    int t = threadIdx.x;
    // fill geometry: threads 0..13 -> x, 64..77 -> y (separate waves)
    if (t < OUT_W * SR) {
        float g = x1 + bin_w * (((float)t + 0.5f) * 0.5f);
        float v = (g >= -1.0f && g <= (float)W_DIM) ? 1.0f : 0.0f;
        float x = fminf(fmaxf(g, 0.0f), (float)(W_DIM - 1));
        int   lo = (int)floorf(x);
        float l  = x - (float)lo;
        xg[t].lo = lo; xg[t].hi = min(lo + 1, W_DIM - 1);
        xg[t].wv = l * v; xg[t].mwv = (1.0f - l) * v;
    } else if (t >= 64 && t < 64 + OUT_H * SR) {
        int i = t - 64;
        float g = y1 + bin_h * (((float)i + 0.5f) * 0.5f);
        float v = (g >= -1.0f && g <= (float)H_DIM) ? 1.0f : 0.0f;
        float y = fminf(fmaxf(g, 0.0f), (float)(H_DIM - 1));
        int   lo = (int)floorf(y);
        float l  = y - (float)lo;
        yg[i].lo = lo; yg[i].hi = min(lo + 1, H_DIM - 1);
        yg[i].wv = l * v; yg[i].mwv = (1.0f - l) * v;
    }
    __syncthreads();

    int wave = t >> 6;
    int lane = t & 63;
    int q    = lane >> 4;                  // corner: 0=ll 1=lh 2=hl 3=hh
    int c    = lane & 15;                  // 8-channel group within half
    int qy   = q >> 1;
    int qx   = q & 1;

    const char* img = (const char*)(nhwc + (size_t)b * HW * C_DIM + h * 128 + c * 8);

    // compute this lane's 4 sample {byte offset, weight} for bin bb
    auto addr_w = [&](int bb, int* off, float* ww) {
        int oh = bb / OUT_W;
        int ow = bb - oh * OUT_W;
        Geom gy0 = yg[oh * SR + 0];
        Geom gy1 = yg[oh * SR + 1];
        Geom gx0 = xg[ow * SR + 0];
        Geom gx1 = xg[ow * SR + 1];
        int   yy0 = qy ? gy0.hi : gy0.lo;  float wy0 = qy ? gy0.wv : gy0.mwv;
        int   yy1 = qy ? gy1.hi : gy1.lo;  float wy1 = qy ? gy1.wv : gy1.mwv;
        int   xx0 = qx ? gx0.hi : gx0.lo;  float wx0 = qx ? gx0.wv : gx0.mwv;
        int   xx1 = qx ? gx1.hi : gx1.lo;  float wx1 = qx ? gx1.wv : gx1.mwv;
        off[0] = (yy0 * W_DIM + xx0) * (C_DIM * 2);  ww[0] = wy0 * wx0;
        off[1] = (yy0 * W_DIM + xx1) * (C_DIM * 2);  ww[1] = wy0 * wx1;
        off[2] = (yy1 * W_DIM + xx0) * (C_DIM * 2);  ww[2] = wy1 * wx0;
        off[3] = (yy1 * W_DIM + xx1) * (C_DIM * 2);  ww[3] = wy1 * wx1;
    };
    auto loads = [&](const int* off, uint4* v) {
        #pragma unroll
        for (int s = 0; s < 4; ++s)
            v[s] = *(const uint4*)(img + off[s]);
    };
    auto proc = [&](int bb, const float* ww, const uint4* v) {
        float acc[8] = {0.f, 0.f, 0.f, 0.f, 0.f, 0.f, 0.f, 0.f};
        #pragma unroll
        for (int s = 0; s < 4; ++s) {
            float w = ww[s];
            #define ACCP(j, u) { \
                acc[2*(j)+0] = fmaf(w, __uint_as_float((u) << 16),          acc[2*(j)+0]); \
                acc[2*(j)+1] = fmaf(w, __uint_as_float((u) & 0xffff0000u),  acc[2*(j)+1]); }
            ACCP(0, v[s].x) ACCP(1, v[s].y) ACCP(2, v[s].z) ACCP(3, v[s].w)
            #undef ACCP
        }
        // reduce the 4 corners: lanes {c, c+16, c+32, c+48} hold partials
        #pragma unroll
        for (int j = 0; j < 8; ++j) {
            acc[j] += __shfl_xor(acc[j], 16);
            acc[j] += __shfl_xor(acc[j], 32);
        }
        if (q == 0) {
            #pragma unroll
            for (int j = 0; j < 8; ++j)
                s_out[(c * 8 + j) * NBINS + bb] = acc[j] * 0.25f;
        }
    };

    // 2-bin software pipeline over strided bins (wave, wave+4, ...)
    int offA[4], offB[4];
    float wwA[4], wwB[4];
    uint4 vA[4], vB[4];

    int bin = wave;
    addr_w(bin, offA, wwA);
    loads(offA, vA);
    while (true) {
        int nb = bin + 4;
        if (nb < NBINS) { addr_w(nb, offB, wwB); loads(offB, vB); }
        proc(bin, wwA, vA);
        bin = nb;
        if (bin >= NBINS) break;
        nb = bin + 4;
        if (nb < NBINS) { addr_w(nb, offA, wwA); loads(offA, vA); }
        proc(bin, wwB, vB);
        bin = nb;
        if (bin >= NBINS) break;
    }
    __syncthreads();

    // coalesced nontemporal copy-out: 6272 floats = 1568 float4, contiguous
    nfloat4* o4 = (nfloat4*)(out + (size_t)k * (C_DIM * NBINS) + (size_t)h * 128 * NBINS);
    const nfloat4* s4 = (const nfloat4*)s_out;
    for (int i = t; i < (128 * NBINS) / 4; i += 256)
        __builtin_nontemporal_store(s4[i], o4 + i);
}

// ---------------- fallback (round-0 baseline) if ws too small ---------------
__global__ __launch_bounds__(256) void roi_align_naive(
    const float* __restrict__ input, const float* __restrict__ rois,
    float* __restrict__ out, int K)
{
    int idx = blockIdx.x * blockDim.x + threadIdx.x;
    int total = K * C_DIM * OUT_H * OUT_W;
    if (idx >= total) return;
    int ow = idx % OUT_W;
    int oh = (idx / OUT_W) % OUT_H;
    int c  = (idx / (OUT_W * OUT_H)) % C_DIM;
    int k  = idx / (OUT_W * OUT_H * C_DIM);
    const float* r = rois + (size_t)k * 5;
    int   b  = (int)r[0];
    float x1 = r[1] * SPATIAL_SCALE, y1 = r[2] * SPATIAL_SCALE;
    float x2 = r[3] * SPATIAL_SCALE, y2 = r[4] * SPATIAL_SCALE;
    float roi_w = fmaxf(x2 - x1, 1.0f), roi_h = fmaxf(y2 - y1, 1.0f);
    float bin_h = roi_h / OUT_H, bin_w = roi_w / OUT_W;
    const float* inp = input + ((size_t)b * C_DIM + c) * HW;
    float acc = 0.0f;
    #pragma unroll
    for (int sy = 0; sy < SR; ++sy) {
        float gy = y1 + bin_h * (((float)(oh * SR + sy) + 0.5f) / SR);
        bool vy = (gy >= -1.0f) && (gy <= (float)H_DIM);
        float y = fminf(fmaxf(gy, 0.0f), (float)(H_DIM - 1));
        int yl = (int)floorf(y); float ly = y - yl; int yh = min(yl + 1, H_DIM - 1);
        #pragma unroll
        for (int sx = 0; sx < SR; ++sx) {
            float gx = x1 + bin_w * (((float)(ow * SR + sx) + 0.5f) / SR);
            bool vx = (gx >= -1.0f) && (gx <= (float)W_DIM);
            float x = fminf(fmaxf(gx, 0.0f), (float)(W_DIM - 1));
            int xl = (int)floorf(x); float lx = x - xl; int xh = min(xl + 1, W_DIM - 1);
            float v = (1.0f - ly) * ((1.0f - lx) * inp[yl * W_DIM + xl] + lx * inp[yl * W_DIM + xh])
                    + ly * ((1.0f - lx) * inp[yh * W_DIM + xl] + lx * inp[yh * W_DIM + xh]);
            if (vy && vx) acc += v;
        }
    }
    out[idx] = acc * 0.25f;
}

extern "C" void kernel_launch(void* const* d_in, const int* in_sizes, int n_in,
                              void* d_out, int out_size, void* d_ws, size_t ws_size,
                              hipStream_t stream) {
    const float* input = (const float*)d_in[0];
    const float* rois  = (const float*)d_in[1];
    float* out = (float*)d_out;
    int K = in_sizes[1] / 5;
    int ntiles = (HW + 63) / 64;    // 157

    if (ws_size >= NHWC_BF16_BYTES + (size_t)K * sizeof(int) && K <= MAX_BUCKET_K) {
        unsigned short* nhwc = (unsigned short*)d_ws;
        int* map = (int*)((char*)d_ws + NHWC_BF16_BYTES);
        dim3 tgrid(ntiles + 1, C_DIM / 64, N_DIM);   // 158 x 4 x 8 (+1 = bucket block)
        nchw_to_nhwc_bf16<<<tgrid, 256, 0, stream>>>(input, nhwc, rois, K, map);
        dim3 ggrid(K, 2);
        roi_gather_q<<<ggrid, 256, 0, stream>>>(nhwc, rois, map, out, K);
    } else if (ws_size >= NHWC_BF16_BYTES) {
        unsigned short* nhwc = (unsigned short*)d_ws;
        dim3 tgrid(ntiles, C_DIM / 64, N_DIM);
        nchw_to_nhwc_bf16<<<tgrid, 256, 0, stream>>>(input, nhwc, rois, K, nullptr);
        dim3 ggrid(K, 2);
        roi_gather_q<<<ggrid, 256, 0, stream>>>(nhwc, rois, nullptr, out, K);
    } else {
        int total = K * C_DIM * OUT_H * OUT_W;
        roi_align_naive<<<(total + 255) / 256, 256, 0, stream>>>(input, rois, out, K);
    }
}